// Round 12
// baseline (76.657 us; speedup 1.0000x reference)
//
#include <hip/hip_runtime.h>
#include <stdint.h>

#define BB 32
#define NN 8000
#define MM 256
#define LL (NN + MM)        // 8256
#define NSAMP 512
#define MAXPOS 128
#define T2 1024
#define CH ((LL + T2 - 1) / T2)   // 9

// forbid fp-contract across this value (exact-path: match numpy rounding)
__device__ __forceinline__ void opaquef(float& x) { asm("" : "+v"(x)); }

// exact reference semantics over the compacted valid-gt list (rare fallback);
// compacted order preserves ascending original m -> first-argmax correct.
__device__ __noinline__ int serial_argmax_q(const float4 bx, const float a1,
                                            const float4* s_gt, const float* s_a2,
                                            int nv, float* outQ)
{
    float qb = -1.0f; int bi = 0;
    for (int m = 0; m < nv; ++m) {
        float4 g = s_gt[m];
        float ih = fmaxf(fminf(bx.z, g.z) - fmaxf(bx.x, g.x), 0.0f);
        float iw = fmaxf(fminf(bx.w, g.w) - fmaxf(bx.y, g.y), 0.0f);
        float inter = ih * iw; opaquef(inter);
        float uni = (a1 + s_a2[m]) - inter;       // numpy op order/rounding
        float q = (uni > 0.0f) ? (inter / uni) : 0.0f;
        if (q > qb) { qb = q; bi = m; }
    }
    *outQ = qb;
    return bi;
}

// ---------------- kernel 1: per-(b,l) argmax over compacted valid gts ------
// R4 geometry (256-thr, 1 box/thread, 1056 blocks) -- the highest measured
// VALUBusy/occupancy shape -- with the leanest inner (~18 VALU + rcp).
// Rank by u = inter/(a1+a2): IoU = u/(1-u) strictly increasing -> same
// argmax. Full 32-bit key = bits of u_approx (= inter * v_rcp(s), err <~2
// ulp); idx via strict-> cndmask (first-argmax on equal keys). If
// best - sec > 32 ulp, true-u order and the reference's ROUNDED-quotient
// order are provably identical (32 ulp ≈ 2^-19 rel >> all rounding); else
// exact serial redo. Compaction (ballot+prefix) removes invalid gts: they
// can never win (inter==0 for every box) and excluding them eliminates all
// NaN (compacted a2 > 0 => s = a1+a2 > 0). Classification: ONE exact
// reference-rounded IoU + IEEE division of the winner pair.
__global__ __launch_bounds__(256) void match_kernel(
    const float* __restrict__ boxes, const float* __restrict__ gt,
    uint16_t* __restrict__ pk)
{
    __shared__ float4   s_gt[MM];
    __shared__ float    s_a2[MM];
    __shared__ uint16_t s_morig[MM];
    __shared__ int      s_wc[4];
    const int b = blockIdx.y, tid = threadIdx.x;
    const int w = tid >> 6, lane = tid & 63;
    const float4* bb4 = (const float4*)(boxes + (size_t)b * NN * 4);
    const float4* gb4 = (const float4*)(gt + (size_t)b * MM * 4);

    {   // stage + compact valid gts (order = ascending original m)
        float4 v = gb4[tid];
        bool valid = !(fmaxf(fmaxf(v.x, v.y), fmaxf(v.z, v.w)) < 0.0f);
        uint64_t mk = __ballot(valid);
        if (lane == 0) s_wc[w] = (int)__popcll(mk);
        __syncthreads();
        int base = 0;
        #pragma unroll
        for (int i = 0; i < 3; ++i) if (i < w) base += s_wc[i];
        if (valid) {
            int pos = base + (int)__popcll(mk & ((1ull << lane) - 1));
            s_gt[pos] = v;
            s_a2[pos] = (v.z - v.x) * (v.w - v.y);  // LDS round-trip blocks fma
            s_morig[pos] = (uint16_t)tid;
        }
    }
    __syncthreads();
    const int nv = s_wc[0] + s_wc[1] + s_wc[2] + s_wc[3];
    const int l = blockIdx.x * 256 + tid;
    if (l >= LL) return;

    float4 bx = (l < NN) ? bb4[l] : gb4[l - NN];
    if (nv == 0 || fmaxf(fmaxf(bx.x, bx.y), fmaxf(bx.z, bx.w)) < 0.0f) {
        // invalid box (or all gts invalid): all sim == -1 -> cls invalid,
        // argmax = 0 (outputs nulled downstream anyway)
        pk[(size_t)b * LL + l] = 2;
        return;
    }
    float a1 = (bx.z - bx.x) * (bx.w - bx.y); opaquef(a1);

    uint32_t best = 0, sec = 0; int idx = 0;
    #pragma unroll 4
    for (int mc = 0; mc < nv; ++mc) {
        float4 g = s_gt[mc];
        float a2 = s_a2[mc];
        float ih = fmaxf(fminf(bx.z, g.z) - fmaxf(bx.x, g.x), 0.0f);
        float iw = fmaxf(fminf(bx.w, g.w) - fmaxf(bx.y, g.y), 0.0f);
        float inter = ih * iw;
        float s = a1 + a2;                         // > 0 (a2 > 0 compacted)
        float u = inter * __builtin_amdgcn_rcpf(s);
        uint32_t key = __float_as_uint(u);
        bool win = key > best;
        sec  = max(sec, min(best, key));           // runner-up (old best|key)
        best = max(best, key);
        idx  = win ? mc : idx;
    }

    int cls, midx;
    if (best != 0u && (best - sec) <= 32u) {
        float qb;                                  // rare: exact serial
        int bi = serial_argmax_q(bx, a1, s_gt, s_a2, nv, &qb);
        midx = s_morig[bi];
        cls = (qb >= 0.5f) ? 1 : 0;
    } else {
        midx = s_morig[idx];
        float4 g = s_gt[idx];
        float ih = fmaxf(fminf(bx.z, g.z) - fmaxf(bx.x, g.x), 0.0f);
        float iw = fmaxf(fminf(bx.w, g.w) - fmaxf(bx.y, g.y), 0.0f);
        float inter = ih * iw; opaquef(inter);
        float uni = (a1 + s_a2[idx]) - inter;      // numpy op order/rounding
        float q = (uni > 0.0f) ? (inter / uni) : 0.0f;   // exact IEEE div
        cls = (q >= 0.5f) ? 1 : 0;   // searchsorted([0,.5,.5], right)
    }
    pk[(size_t)b * LL + l] = (uint16_t)(cls | (midx << 2));
}

// ---------------- scans ----------------
__device__ __forceinline__ int block_exscan_fast(int v, int* wt, int tid)
{
    const int lane = tid & 63, w = tid >> 6;
    int x = v;
    #pragma unroll
    for (int off = 1; off < 64; off <<= 1) {
        int y = __shfl_up(x, off);
        if (lane >= off) x += y;
    }
    if (lane == 63) wt[w] = x;
    __syncthreads();
    if (tid < 64) {
        int t = (tid < 16) ? wt[tid] : 0;
        #pragma unroll
        for (int off = 1; off < 16; off <<= 1) {
            int y = __shfl_up(t, off);
            if (tid >= off) t += y;
        }
        if (tid < 16) wt[tid] = t;
    }
    __syncthreads();
    return ((w > 0) ? wt[w - 1] : 0) + x - v;
}

__device__ __forceinline__ int block_exscan_seg4(int v, int* wt, int tid)
{
    const int lane = tid & 63, w = tid >> 6;
    int x = v;
    #pragma unroll
    for (int off = 1; off < 64; off <<= 1) {
        int y = __shfl_up(x, off);
        if (lane >= off) x += y;
    }
    if (lane == 63) wt[w] = x;
    __syncthreads();
    if (tid < 16) {
        int t = wt[tid];
        #pragma unroll
        for (int off = 1; off < 4; off <<= 1) {
            int y = __shfl_up(t, off);
            if ((tid & 3) >= off) t += y;
        }
        wt[tid] = t;
    }
    __syncthreads();
    return (((w & 3) > 0) ? wt[w - 1] : 0) + x - v;
}

// ---------------- kernel 2: per-batch sampling + gather --------------------
// s_pk bit layout: [1:0] cls, [9:2] matched gt idx, [15] sel flag
__global__ __launch_bounds__(T2) void sample_kernel(
    const float* __restrict__ boxes, const float* __restrict__ gt,
    const int* __restrict__ gtc, const float* __restrict__ rnd,
    const uint16_t* __restrict__ pk, float* __restrict__ out)
{
    __shared__ uint32_t s_key[LL];
    __shared__ uint16_t s_pk[LL];
    __shared__ int s_hist[512];
    __shared__ int s_warp[16];
    __shared__ int s_idx[NSAMP];
    __shared__ int s_sb[8];
    const int b = blockIdx.x, tid = threadIdx.x, lane = tid & 63;
    const float4* bb4 = (const float4*)(boxes + (size_t)b * NN * 4);
    const float4* gb4 = (const float4*)(gt + (size_t)b * MM * 4);

    if (tid == 0) s_sb[0] = 0;
    __syncthreads();

    int loc = 0;
    for (int l = tid; l < LL; l += T2) {
        s_key[l] = __float_as_uint(rnd[(size_t)b * LL + l]);
        uint16_t p = pk[(size_t)b * LL + l];
        s_pk[l] = p;
        int c = p & 3;
        loc += (c == 0) ? 1 : ((c == 1) ? 0x10000 : 0);
    }
    #pragma unroll
    for (int off = 32; off; off >>= 1) loc += __shfl_xor(loc, off);
    if (lane == 0) atomicAdd(&s_sb[0], loc);
    __syncthreads();
    const int Nn = s_sb[0] & 0xFFFF, P = s_sb[0] >> 16;

    const int posK = (P < MAXPOS) ? P : MAXPOS;
    const int negK = NSAMP - posK;
    const bool negRad = (Nn > negK);
    const bool posRad = (P > MAXPOS);

    uint32_t prefix0 = 0, prefix1 = 0;
    int rem0 = negK, rem1 = MAXPOS;
    if (negRad || posRad) {
        for (int round = 0; round < 4; ++round) {
            const int shift = 24 - 8 * round;
            if (tid < 512) s_hist[tid] = 0;
            __syncthreads();
            const uint32_t pmask = (round == 0) ? 0u : (0xFFFFFFFFu << (shift + 8));
            for (int l = tid; l < LL; l += T2) {
                const uint32_t k = s_key[l];
                const int c = s_pk[l] & 3;
                bool doit = (c == 0) ? (negRad && ((k & pmask) == prefix0))
                          : (c == 1) ? (posRad && ((k & pmask) == prefix1))
                          : false;
                if (doit) atomicAdd(&s_hist[(c << 8) | ((k >> shift) & 255)], 1);
            }
            __syncthreads();
            int h = 0;
            if (tid < 512) h = s_hist[(tid & 0x100) | (255 - (tid & 255))];
            const int above = block_exscan_seg4(h, s_warp, tid);
            if (tid < 512) {
                const int c = tid >> 8;
                const int rem = c ? rem1 : rem0;
                const bool act = c ? posRad : negRad;
                if (act && above < rem && above + h >= rem) {
                    s_sb[4 + c * 2] = 255 - (tid & 255);
                    s_sb[5 + c * 2] = above;
                }
            }
            __syncthreads();
            if (negRad) { prefix0 |= ((uint32_t)s_sb[4]) << shift; rem0 -= s_sb[5]; }
            if (posRad) { prefix1 |= ((uint32_t)s_sb[6]) << shift; rem1 -= s_sb[7]; }
            __syncthreads();
        }
    }
    const uint32_t thr0 = negRad ? prefix0 : 0u;  const int r0 = negRad ? rem0 : LL;
    const uint32_t thr1 = posRad ? prefix1 : 0u;  const int r1 = posRad ? rem1 : LL;

    const int lo = tid * CH, hi = (lo + CH < LL) ? (lo + CH) : LL;
    int nt = 0;
    for (int l = lo; l < hi; ++l) {
        const int c = s_pk[l] & 3;
        const uint32_t k = s_key[l];
        if (c == 0) { if (k == thr0) nt += 1; }
        else if (c == 1) { if (k == thr1) nt += 0x10000; }
    }
    const int basep = block_exscan_fast(nt, s_warp, tid);
    int base0 = basep & 0xFFFF, base1 = basep >> 16;
    for (int l = lo; l < hi; ++l) {
        const int c = s_pk[l] & 3;
        if (c > 1) continue;
        const uint32_t k = s_key[l];
        const uint32_t thr = c ? thr1 : thr0;
        bool sel = (k > thr);
        if (k == thr) {
            if (c == 0) { sel = (base0 < r0); ++base0; }
            else        { sel = (base1 < r1); ++base1; }
        }
        if (sel) s_pk[l] |= 0x8000;
    }
    __syncthreads();

    int cnt = 0;
    for (int l = lo; l < hi; ++l) cnt += (s_pk[l] & 0x8000) ? 1 : 0x10000;
    const int pb = block_exscan_fast(cnt, s_warp, tid);
    const int S = s_warp[15] & 0xFFFF;
    int bs = pb & 0xFFFF, bu = (pb >> 16) + S;
    for (int l = lo; l < hi; ++l) {
        if (s_pk[l] & 0x8000) { if (bs < NSAMP) s_idx[bs] = l; ++bs; }
        else                  { if (bu < NSAMP) s_idx[bu] = l; ++bu; }
    }
    __syncthreads();

    if (tid < NSAMP) {
        const int l = s_idx[tid];
        float4 bx = (l < NN) ? bb4[l] : gb4[l - NN];
        const int p = s_pk[l];
        const int c = p & 3, mi = (p >> 2) & 0xFF;
        const bool bg = (c != 1);          // background = matched_val < 0.5
        float4 gb = make_float4(0.f, 0.f, 0.f, 0.f);
        int cl = 0, si = -1;
        if (!bg) {
            gb = gb4[mi];
            cl = gtc[(size_t)b * MM + mi];
            si = mi;
        }
        const size_t rk = (size_t)b * NSAMP + tid;
        ((float4*)out)[rk] = bx;                                   // rois
        ((float4*)(out + (size_t)BB * NSAMP * 4))[rk] = gb;        // sampled_gt_boxes
        out[(size_t)2 * BB * NSAMP * 4 + rk] = (float)cl;          // classes
        out[(size_t)2 * BB * NSAMP * 4 + (size_t)BB * NSAMP + rk] = (float)si; // indices
    }
}

extern "C" void kernel_launch(void* const* d_in, const int* in_sizes, int n_in,
                              void* d_out, int out_size, void* d_ws, size_t ws_size,
                              hipStream_t stream)
{
    const float* boxes = (const float*)d_in[0];   // [32,8000,4] f32
    const float* gt    = (const float*)d_in[1];   // [32,256,4]  f32
    const int*   gtc   = (const int*)  d_in[2];   // [32,256]    i32
    const float* rnd   = (const float*)d_in[3];   // [32,8256]   f32
    float* out = (float*)d_out;
    uint16_t* pk = (uint16_t*)d_ws;               // BB*LL*2 = 516 KB

    dim3 g1((LL + 255) / 256, BB);                // 33,32 = 1056 blocks
    match_kernel<<<g1, 256, 0, stream>>>(boxes, gt, pk);
    sample_kernel<<<BB, T2, 0, stream>>>(boxes, gt, gtc, rnd, pk, out);
}

// Round 13
// 68.326 us; speedup vs baseline: 1.1219x; 1.1219x over previous
//
#include <hip/hip_runtime.h>
#include <stdint.h>

#define BB 32
#define NN 8000
#define MM 256
#define LL (NN + MM)        // 8256
#define NSAMP 512
#define MAXPOS 128
#define T2 1024
#define CH ((LL + T2 - 1) / T2)   // 9
#define SPLIT 4
#define MSUB (MM / SPLIT)   // 64

// forbid fp-contract across this value (exact-path: match numpy rounding)
__device__ __forceinline__ void opaquef(float& x) { asm("" : "+v"(x)); }

// exact reference semantics over the compacted valid-gt list (rare fallback)
__device__ __noinline__ int serial_argmax(const float4 bx, const float a1,
                                          const float4* s_gt, const float* s_a2,
                                          int nv)
{
    float qb = -1.0f; int bi = 0;
    for (int m = 0; m < nv; ++m) {
        float4 g = s_gt[m];
        float ih = fmaxf(fminf(bx.z, g.z) - fmaxf(bx.x, g.x), 0.0f);
        float iw = fmaxf(fminf(bx.w, g.w) - fmaxf(bx.y, g.y), 0.0f);
        float inter = ih * iw; opaquef(inter);
        float uni = (a1 + s_a2[m]) - inter;
        float q = (uni > 0.0f) ? (inter / uni) : 0.0f;
        if (q > qb) { qb = q; bi = m; }
    }
    return bi;    // compacted index (ascending original order preserved)
}

__device__ __forceinline__ uint32_t approx_key(const float4 bx, float a1,
                                               const float4 g, float a2,
                                               uint32_t klo)
{
    float ih = fmaxf(fminf(bx.z, g.z) - fmaxf(bx.x, g.x), 0.0f);
    float iw = fmaxf(fminf(bx.w, g.w) - fmaxf(bx.y, g.y), 0.0f);
    float inter = ih * iw;
    float s = a1 + a2;                             // > 0 (a2 > 0 compacted)
    float u = inter * __builtin_amdgcn_rcpf(s);
    return (__float_as_uint(u) & 0xFFFFFFC0u) | klo;
}

// ---------------- kernel 1: per-(b, box, split) argmax over valid gts ------
// R4 geometry (SPLIT=4 x BPT=1 x 256 thr = 16896 waves: the only shape that
// reached 82% VALUBusy) with R8's lean truncated-key inner (~16 VALU + rcp).
// Rank by u = inter/(a1+a2) (monotone in IoU). key = (u_bits & ~63)|(63-m):
// argmax is ONE v_max_u32; truncated-u ties pick smaller original m. Winner
// is provably the reference's rounded-quotient argmax when the truncated gap
// to the runner-up exceeds 64 ulp; else exact serial redo (rare). Valid gts
// compacted via ballot (split 3 is all-invalid in this data -> nv=0, block
// exits instantly); invalid gts can never win (inter==0 for every box) and
// compaction removes all NaN risk (a2 > 0 => s > 0).
__global__ __launch_bounds__(256) void match_split_kernel(
    const float* __restrict__ boxes, const float* __restrict__ gt,
    uint32_t* __restrict__ keys)
{
    __shared__ float4 s_gt[MSUB];
    __shared__ float  s_a2[MSUB];
    __shared__ uint32_t s_klo[MSUB];
    __shared__ int s_nv;
    const int b = blockIdx.y, sp = blockIdx.z, tid = threadIdx.x;
    if (tid < MSUB) {   // tid 0..63 == wave 0 exactly
        float4 v = ((const float4*)(gt + ((size_t)b * MM + sp * MSUB) * 4))[tid];
        bool valid = !(fmaxf(fmaxf(v.x, v.y), fmaxf(v.z, v.w)) < 0.0f);
        uint64_t mk = __ballot(valid);
        int pos = __popcll(mk & ((1ull << tid) - 1));
        if (valid) {
            s_gt[pos] = v;
            s_a2[pos] = (v.z - v.x) * (v.w - v.y);
            s_klo[pos] = (uint32_t)(63 - tid);   // original index in low bits
        }
        if (tid == 0) s_nv = (int)__popcll(mk);
    }
    __syncthreads();
    const int l = blockIdx.x * 256 + tid;
    if (l >= LL) return;
    const int nv = s_nv;

    const float4* bb4 = (const float4*)(boxes + (size_t)b * NN * 4);
    const float4* gb4 = (const float4*)(gt + (size_t)b * MM * 4);
    float4 bx = (l < NN) ? bb4[l] : gb4[l - NN];
    float a1 = (bx.z - bx.x) * (bx.w - bx.y); opaquef(a1);

    uint32_t best = 0, sec = 0;
    #pragma unroll 4
    for (int m = 0; m < nv; ++m) {
        uint32_t key = approx_key(bx, a1, s_gt[m], s_a2[m], s_klo[m]);
        sec  = max(sec, min(best, key));
        best = max(best, key);
    }

    bool redo = ((best & ~63u) != 0u) &&
                (((best & ~63u) - (sec & ~63u)) <= 64u);
    if (__any(redo)) {
        if (redo) {
            int w = serial_argmax(bx, a1, s_gt, s_a2, nv);
            best = approx_key(bx, a1, s_gt[w], s_a2[w], s_klo[w]);
        }
    }
    keys[((size_t)b * LL + l) * SPLIT + sp] = best;
}

// ---------------- kernel 1b: cross-split winner + classify (1056 blocks) ---
// Picks the winner with 3 uint max (strict >, lower split keeps on tie).
// Truncated gap > 64 ulp to the other splits -> ONE exact reference-rounded
// IoU+div classifies; else exact 4-way re-merge. Writes u16 cls|midx
// IN-PLACE at the head of this l's own 16-byte key slot.
__global__ __launch_bounds__(256) void merge2_kernel(
    const float* __restrict__ boxes, const float* __restrict__ gt,
    uint32_t* __restrict__ keys)
{
    const int b = blockIdx.y;
    const int l = blockIdx.x * 256 + threadIdx.x;
    if (l >= LL) return;
    const float4* bb4 = (const float4*)(boxes + (size_t)b * NN * 4);
    const float4* gb4 = (const float4*)(gt + (size_t)b * MM * 4);
    const uint4 kv = ((const uint4*)keys)[(size_t)b * LL + l];
    float4 bx = (l < NN) ? bb4[l] : gb4[l - NN];
    int cls, midx = 0;
    uint32_t best = kv.x; int bsp = 0;
    if (kv.y > best) { best = kv.y; bsp = 1; }
    if (kv.z > best) { best = kv.z; bsp = 2; }
    if (kv.w > best) { best = kv.w; bsp = 3; }
    if (fmaxf(fmaxf(bx.x, bx.y), fmaxf(bx.z, bx.w)) < 0.0f || best == 0u) {
        cls = 2;   // invalid box (or all gts invalid): all sim == -1
    } else {
        const uint32_t bt = best & ~63u;
        const uint32_t s0 = (bsp == 0) ? 0u : (kv.x & ~63u);
        const uint32_t s1 = (bsp == 1) ? 0u : (kv.y & ~63u);
        const uint32_t s2 = (bsp == 2) ? 0u : (kv.z & ~63u);
        const uint32_t s3 = (bsp == 3) ? 0u : (kv.w & ~63u);
        const uint32_t sec = max(max(s0, s1), max(s2, s3));
        float a1 = (bx.z - bx.x) * (bx.w - bx.y); opaquef(a1);
        if ((bt != 0u) && (bt - sec) <= 64u) {
            // ambiguous across splits: exact 4-way, split ascending, strict >
            float qb = -1.0f; midx = 0;
            #pragma unroll
            for (int sp = 0; sp < SPLIT; ++sp) {
                const uint32_t k = (sp == 0) ? kv.x : (sp == 1) ? kv.y
                                 : (sp == 2) ? kv.z : kv.w;
                const int m = sp * MSUB + (63 - (int)(k & 63u));
                float4 g = gb4[m];
                float a2 = (g.z - g.x) * (g.w - g.y); opaquef(a2);
                float ih = fmaxf(fminf(bx.z, g.z) - fmaxf(bx.x, g.x), 0.0f);
                float iw = fmaxf(fminf(bx.w, g.w) - fmaxf(bx.y, g.y), 0.0f);
                float inter = ih * iw; opaquef(inter);
                float uni = (a1 + a2) - inter;
                float q = (uni > 0.0f) ? (inter / uni) : 0.0f;
                if (q > qb) { qb = q; midx = m; }
            }
            cls = (qb >= 0.5f) ? 1 : 0;
        } else {
            midx = bsp * MSUB + (63 - (int)(best & 63u));
            float4 g = gb4[midx];
            float a2 = (g.z - g.x) * (g.w - g.y); opaquef(a2);
            float ih = fmaxf(fminf(bx.z, g.z) - fmaxf(bx.x, g.x), 0.0f);
            float iw = fmaxf(fminf(bx.w, g.w) - fmaxf(bx.y, g.y), 0.0f);
            float inter = ih * iw; opaquef(inter);
            float uni = (a1 + a2) - inter;     // numpy op order/rounding
            float q = (uni > 0.0f) ? (inter / uni) : 0.0f;   // exact reference
            cls = (q >= 0.5f) ? 1 : 0;         // searchsorted([0,.5,.5], right)
        }
    }
    ((uint16_t*)keys)[((size_t)b * LL + l) * 8] = (uint16_t)(cls | (midx << 2));
}

// ---------------- scans ----------------
__device__ __forceinline__ int block_exscan_fast(int v, int* wt, int tid)
{
    const int lane = tid & 63, w = tid >> 6;
    int x = v;
    #pragma unroll
    for (int off = 1; off < 64; off <<= 1) {
        int y = __shfl_up(x, off);
        if (lane >= off) x += y;
    }
    if (lane == 63) wt[w] = x;
    __syncthreads();
    if (tid < 64) {
        int t = (tid < 16) ? wt[tid] : 0;
        #pragma unroll
        for (int off = 1; off < 16; off <<= 1) {
            int y = __shfl_up(t, off);
            if (tid >= off) t += y;
        }
        if (tid < 16) wt[tid] = t;
    }
    __syncthreads();
    return ((w > 0) ? wt[w - 1] : 0) + x - v;
}

__device__ __forceinline__ int block_exscan_seg4(int v, int* wt, int tid)
{
    const int lane = tid & 63, w = tid >> 6;
    int x = v;
    #pragma unroll
    for (int off = 1; off < 64; off <<= 1) {
        int y = __shfl_up(x, off);
        if (lane >= off) x += y;
    }
    if (lane == 63) wt[w] = x;
    __syncthreads();
    if (tid < 16) {
        int t = wt[tid];
        #pragma unroll
        for (int off = 1; off < 4; off <<= 1) {
            int y = __shfl_up(t, off);
            if ((tid & 3) >= off) t += y;
        }
        wt[tid] = t;
    }
    __syncthreads();
    return (((w & 3) > 0) ? wt[w - 1] : 0) + x - v;
}

// ---------------- kernel 2: per-batch sampling + gather --------------------
// s_pk bit layout: [1:0] cls, [9:2] matched gt idx, [15] sel flag
__global__ __launch_bounds__(T2) void sample_kernel(
    const float* __restrict__ boxes, const float* __restrict__ gt,
    const int* __restrict__ gtc, const float* __restrict__ rnd,
    const uint32_t* __restrict__ keys, float* __restrict__ out)
{
    __shared__ uint32_t s_key[LL];
    __shared__ uint16_t s_pk[LL];
    __shared__ int s_hist[512];
    __shared__ int s_warp[16];
    __shared__ int s_idx[NSAMP];
    __shared__ int s_sb[8];
    const int b = blockIdx.x, tid = threadIdx.x, lane = tid & 63;
    const float4* bb4 = (const float4*)(boxes + (size_t)b * NN * 4);
    const float4* gb4 = (const float4*)(gt + (size_t)b * MM * 4);

    if (tid == 0) s_sb[0] = 0;
    __syncthreads();

    int loc = 0;
    for (int l = tid; l < LL; l += T2) {
        s_key[l] = __float_as_uint(rnd[(size_t)b * LL + l]);
        uint16_t p = ((const uint16_t*)keys)[((size_t)b * LL + l) * 8];
        s_pk[l] = p;
        int c = p & 3;
        loc += (c == 0) ? 1 : ((c == 1) ? 0x10000 : 0);
    }
    #pragma unroll
    for (int off = 32; off; off >>= 1) loc += __shfl_xor(loc, off);
    if (lane == 0) atomicAdd(&s_sb[0], loc);
    __syncthreads();
    const int Nn = s_sb[0] & 0xFFFF, P = s_sb[0] >> 16;

    const int posK = (P < MAXPOS) ? P : MAXPOS;
    const int negK = NSAMP - posK;
    const bool negRad = (Nn > negK);
    const bool posRad = (P > MAXPOS);

    // --- fused dual-class radix select with whole-bin early exit ---
    // When remaining == count in the crossing bin, ALL of that bin is taken:
    // thr = prefix (lower bits 0) + rem = LL selects exactly bins>bin plus
    // the whole bin -> later rounds unnecessary.
    uint32_t prefix0 = 0, prefix1 = 0;
    int rem0 = negK, rem1 = MAXPOS;
    bool act0 = negRad, act1 = posRad;
    uint32_t thr0f = 0, thr1f = 0;
    int r0f = LL, r1f = LL;
    for (int round = 0; round < 4 && (act0 || act1); ++round) {
        const int shift = 24 - 8 * round;
        if (tid < 512) s_hist[tid] = 0;
        __syncthreads();
        const uint32_t pmask = (round == 0) ? 0u : (0xFFFFFFFFu << (shift + 8));
        for (int l = tid; l < LL; l += T2) {
            const uint32_t k = s_key[l];
            const int c = s_pk[l] & 3;
            bool doit = (c == 0) ? (act0 && ((k & pmask) == prefix0))
                      : (c == 1) ? (act1 && ((k & pmask) == prefix1))
                      : false;
            if (doit) atomicAdd(&s_hist[(c << 8) | ((k >> shift) & 255)], 1);
        }
        __syncthreads();
        int h = 0;
        if (tid < 512) h = s_hist[(tid & 0x100) | (255 - (tid & 255))];
        const int above = block_exscan_seg4(h, s_warp, tid);
        if (tid < 512) {
            const int c = tid >> 8;
            const int rem = c ? rem1 : rem0;
            const bool act = c ? act1 : act0;
            if (act && above < rem && above + h >= rem) {
                s_sb[4 + c * 2] = 255 - (tid & 255);
                s_sb[5 + c * 2] = above;
            }
        }
        __syncthreads();
        if (act0) {
            const int bin = s_sb[4];
            rem0 -= s_sb[5];
            prefix0 |= ((uint32_t)bin) << shift;
            const int cnt = s_hist[bin];
            if (rem0 == cnt)      { act0 = false; thr0f = prefix0; r0f = LL; }
            else if (round == 3)  { act0 = false; thr0f = prefix0; r0f = rem0; }
        }
        if (act1) {
            const int bin = s_sb[6];
            rem1 -= s_sb[7];
            prefix1 |= ((uint32_t)bin) << shift;
            const int cnt = s_hist[256 + bin];
            if (rem1 == cnt)      { act1 = false; thr1f = prefix1; r1f = LL; }
            else if (round == 3)  { act1 = false; thr1f = prefix1; r1f = rem1; }
        }
        __syncthreads();
    }
    const uint32_t thr0 = negRad ? thr0f : 0u;  const int r0 = negRad ? r0f : LL;
    const uint32_t thr1 = posRad ? thr1f : 0u;  const int r1 = posRad ? r1f : LL;

    // --- fused mark pass (tie counts packed: neg low16 | pos high16) ---
    const int lo = tid * CH, hi = (lo + CH < LL) ? (lo + CH) : LL;
    int nt = 0;
    for (int l = lo; l < hi; ++l) {
        const int c = s_pk[l] & 3;
        const uint32_t k = s_key[l];
        if (c == 0) { if (k == thr0) nt += 1; }
        else if (c == 1) { if (k == thr1) nt += 0x10000; }
    }
    const int basep = block_exscan_fast(nt, s_warp, tid);
    int base0 = basep & 0xFFFF, base1 = basep >> 16;
    for (int l = lo; l < hi; ++l) {
        const int c = s_pk[l] & 3;
        if (c > 1) continue;
        const uint32_t k = s_key[l];
        const uint32_t thr = c ? thr1 : thr0;
        bool sel = (k > thr);
        if (k == thr) {
            if (c == 0) { sel = (base0 < r0); ++base0; }
            else        { sel = (base1 < r1); ++base1; }
        }
        if (sel) s_pk[l] |= 0x8000;
    }
    __syncthreads();

    // --- compaction: selected ascending then unselected ascending ---
    int cnt = 0;
    for (int l = lo; l < hi; ++l) cnt += (s_pk[l] & 0x8000) ? 1 : 0x10000;
    const int pb = block_exscan_fast(cnt, s_warp, tid);
    const int S = s_warp[15] & 0xFFFF;
    int bs = pb & 0xFFFF, bu = (pb >> 16) + S;
    for (int l = lo; l < hi; ++l) {
        if (s_pk[l] & 0x8000) { if (bs < NSAMP) s_idx[bs] = l; ++bs; }
        else                  { if (bu < NSAMP) s_idx[bu] = l; ++bu; }
    }
    __syncthreads();

    // --- gather + write all 4 outputs (ints written as float values) ---
    if (tid < NSAMP) {
        const int l = s_idx[tid];
        float4 bx = (l < NN) ? bb4[l] : gb4[l - NN];
        const int p = s_pk[l];
        const int c = p & 3, mi = (p >> 2) & 0xFF;
        const bool bg = (c != 1);          // background = matched_val < 0.5
        float4 gb = make_float4(0.f, 0.f, 0.f, 0.f);
        int cl = 0, si = -1;
        if (!bg) {
            gb = gb4[mi];
            cl = gtc[(size_t)b * MM + mi];
            si = mi;
        }
        const size_t rk = (size_t)b * NSAMP + tid;
        ((float4*)out)[rk] = bx;                                   // rois
        ((float4*)(out + (size_t)BB * NSAMP * 4))[rk] = gb;        // sampled_gt_boxes
        out[(size_t)2 * BB * NSAMP * 4 + rk] = (float)cl;          // classes
        out[(size_t)2 * BB * NSAMP * 4 + (size_t)BB * NSAMP + rk] = (float)si; // indices
    }
}

extern "C" void kernel_launch(void* const* d_in, const int* in_sizes, int n_in,
                              void* d_out, int out_size, void* d_ws, size_t ws_size,
                              hipStream_t stream)
{
    const float* boxes = (const float*)d_in[0];   // [32,8000,4] f32
    const float* gt    = (const float*)d_in[1];   // [32,256,4]  f32
    const int*   gtc   = (const int*)  d_in[2];   // [32,256]    i32
    const float* rnd   = (const float*)d_in[3];   // [32,8256]   f32
    float* out = (float*)d_out;
    uint32_t* keys = (uint32_t*)d_ws;             // BB*LL*SPLIT*4 = 4.22 MB

    dim3 g1((LL + 255) / 256, BB, SPLIT);         // 33,32,4 = 4224 blocks
    match_split_kernel<<<g1, 256, 0, stream>>>(boxes, gt, keys);
    dim3 g2((LL + 255) / 256, BB);                // 33,32
    merge2_kernel<<<g2, 256, 0, stream>>>(boxes, gt, keys);
    sample_kernel<<<BB, T2, 0, stream>>>(boxes, gt, gtc, rnd, keys, out);
}